// Round 7
// baseline (35.302 us; speedup 1.0000x reference)
//
#include <hip/hip_runtime.h>
#include <hip/hip_bf16.h>
#include <math.h>

// B=2, L=5, C=32, H=48, W=176, NUM_ITER=1.
// Cuts: only i=0 slice matters (R1); conv = warped-half (per j) + ego-half (per b) (R1);
// conv+mlp on MFMA bf16 (R3); single fused kernel, per-block tile+halo warp (R5/R6).
// R7: coalesced weight pack (float4 reads + LDS scatter writes), wave-owns-channel-group
// staging (per-wave gather working set ~11KB fits L1), unpadded strides (LDS 59KB),
// prologue reordered to hide j0 gather latency under weight pack.
#define BB 2
#define LL 5
#define CC 32
#define HH 48
#define WW 176
#define HWs (HH * WW)     // 8448

#define TR 8              // inner tile rows
#define TC 8              // inner tile cols
#define HR 10             // halo rows
#define HC 10             // halo cols
#define IPS 32            // image pixel stride in LDS (bf16 units; 64B/px, b128-contig)
#define WPS 32            // weight row stride (bf16 units)
#define IMG_ELE (HR * HC * IPS)   // 3200 ushort per staged image

typedef __attribute__((ext_vector_type(8))) short bf16x8;
typedef __attribute__((ext_vector_type(4))) float f32x4;

__device__ __forceinline__ unsigned short f2bf(float v) {
    __hip_bfloat16 h = __float2bfloat16(v);   // RNE
    return *reinterpret_cast<unsigned short*>(&h);
}
__device__ __forceinline__ float bf2f(unsigned short u) {
    __hip_bfloat16 h = *reinterpret_cast<__hip_bfloat16*>(&u);
    return __bfloat162float(h);
}

// ---- bilinear weights/indices for grid_sample(align_corners=False, zeros pad) ----
__device__ __forceinline__ void bilin_weights(const float* __restrict__ Mp, int h, int w,
                                              int& o00, int& o10, int& o01, int& o11,
                                              float& a00, float& a10, float& a01, float& a11)
{
    float xs = (2.0f * (float)w + 1.0f) / (float)WW - 1.0f;
    float ys = (2.0f * (float)h + 1.0f) / (float)HH - 1.0f;
    float gx = Mp[0] * xs + Mp[1] * ys + Mp[2];
    float gy = Mp[3] * xs + Mp[4] * ys + Mp[5];
    float ix = ((gx + 1.0f) * (float)WW - 1.0f) * 0.5f;
    float iy = ((gy + 1.0f) * (float)HH - 1.0f) * 0.5f;
    float x0f = floorf(ix), y0f = floorf(iy);
    float wx = ix - x0f, wy = iy - y0f;
    float x1f = x0f + 1.0f, y1f = y0f + 1.0f;
    bool vx0 = (x0f >= 0.0f) && (x0f <= (float)(WW - 1));
    bool vx1 = (x1f >= 0.0f) && (x1f <= (float)(WW - 1));
    bool vy0 = (y0f >= 0.0f) && (y0f <= (float)(HH - 1));
    bool vy1 = (y1f >= 0.0f) && (y1f <= (float)(HH - 1));
    int xi0 = (int)fminf(fmaxf(x0f, 0.0f), (float)(WW - 1));
    int xi1 = (int)fminf(fmaxf(x1f, 0.0f), (float)(WW - 1));
    int yi0 = (int)fminf(fmaxf(y0f, 0.0f), (float)(HH - 1));
    int yi1 = (int)fminf(fmaxf(y1f, 0.0f), (float)(HH - 1));
    o00 = yi0 * WW + xi0;
    o10 = yi0 * WW + xi1;
    o01 = yi1 * WW + xi0;
    o11 = yi1 * WW + xi1;
    a00 = (vx0 && vy0) ? (1.0f - wx) * (1.0f - wy) : 0.0f;
    a10 = (vx1 && vy0) ? wx * (1.0f - wy) : 0.0f;
    a01 = (vx0 && vy1) ? (1.0f - wx) * wy : 0.0f;
    a11 = (vx1 && vy1) ? wx * wy : 0.0f;
}

// immediate ego stage: one (halo-pixel, 8-ch-group) unit, straight copy of x[b][0]
__device__ __forceinline__ void stage_ego(const float* __restrict__ x,
                                          int b, int px, int cg, int r0, int c0,
                                          unsigned short* __restrict__ dst)
{
    int hr = px / HC, hc = px % HC;
    int gr = r0 + hr - 1, gc = c0 + hc - 1;
    unsigned short* dp = dst + px * IPS + cg * 8;
    if (gr < 0 || gr >= HH || gc < 0 || gc >= WW) {
        const bf16x8 z = {0, 0, 0, 0, 0, 0, 0, 0};
        *(bf16x8*)dp = z;
        return;
    }
    bf16x8 v8;
    const float* ip = x + ((size_t)(b * LL) * CC + cg * 8) * HWs + gr * WW + gc;
#pragma unroll
    for (int c = 0; c < 8; ++c)
        v8[c] = (short)f2bf(ip[(size_t)c * HWs]);
    *(bf16x8*)dp = v8;
}

// T14 part A: compute bilinear coeffs, issue 32 gather loads into regs
__device__ __forceinline__ void pref_A(const float* __restrict__ x,
                                       const float* __restrict__ Mp,
                                       int b, int j, int px, int cg, int r0, int c0,
                                       float* __restrict__ t, float* __restrict__ a, bool& v)
{
    int hr = px / HC, hc = px % HC;
    int gr = r0 + hr - 1, gc = c0 + hc - 1;
    v = !(gr < 0 || gr >= HH || gc < 0 || gc >= WW);
    if (!v) return;
    int o00, o10, o01, o11;
    bilin_weights(Mp, gr, gc, o00, o10, o01, o11, a[0], a[1], a[2], a[3]);
    const float* ip = x + ((size_t)(b * LL + j) * CC + cg * 8) * HWs;
#pragma unroll
    for (int c = 0; c < 8; ++c) {
        const float* q = ip + (size_t)c * HWs;
        t[c * 4 + 0] = q[o00];
        t[c * 4 + 1] = q[o10];
        t[c * 4 + 2] = q[o01];
        t[c * 4 + 3] = q[o11];
    }
}

// T14 part C: combine taps, convert, ds_write
__device__ __forceinline__ void pref_C(unsigned short* __restrict__ dst,
                                       int px, int cg,
                                       const float* __restrict__ t,
                                       const float* __restrict__ a, bool v)
{
    bf16x8 v8 = {0, 0, 0, 0, 0, 0, 0, 0};
    if (v) {
#pragma unroll
        for (int c = 0; c < 8; ++c)
            v8[c] = (short)f2bf(a[0] * t[c * 4] + a[1] * t[c * 4 + 1] +
                                a[2] * t[c * 4 + 2] + a[3] * t[c * 4 + 3]);
    }
    *(bf16x8*)(dst + px * IPS + cg * 8) = v8;
}

__global__ __launch_bounds__(256) void k_all(const float* __restrict__ x,
                                             const float* __restrict__ M,
                                             const float* __restrict__ msg_w,
                                             const float* __restrict__ msg_b,
                                             const float* __restrict__ mlp_w,
                                             const float* __restrict__ mlp_b,
                                             float* __restrict__ out)
{
    __shared__ unsigned short wmsg[2 * 9 * 32 * WPS];   // [half*9+tap][oc][ic]  36864 B
    __shared__ unsigned short wmlp[32 * WPS];           // [d][c]                 2048 B
    __shared__ unsigned short ego[IMG_ELE];             //                        6400 B
    __shared__ alignas(16) unsigned short jbuf[2][IMG_ELE];   // double buffer  12800 B
    __shared__ float maskl[LL][64];                     //                       1280 B

    const int tid = threadIdx.x;
    const int b  = blockIdx.z;
    const int r0 = blockIdx.y * TR;
    const int c0 = blockIdx.x * TC;
    const float* Mb = M + (size_t)b * LL * LL * 6;      // M[b][0][j] = Mb + j*6

    const int wv   = tid >> 6;     // 0..3
    const int lane = tid & 63;
    const int lo   = lane & 15;
    const int kblk = lane >> 4;

    // staging assignment: wave wv owns channel-group cg=wv (L1 line locality:
    // a wave's gathers touch only its 8 planes' 10x10 halo ~ 11KB, fits L1)
    const int spx1 = lane;              // px 0..63
    const int spx2 = 64 + lane;         // px 64..99 (lane<36)
    const bool has2 = (lane < 36);

    float t1[32], a1[4]; bool v1 = false;
    float t2[32], a2[4]; bool v2 = false;

    // ---- P1: issue j=0 gather loads first (fly under the weight pack) ----
    pref_A(x, Mb, b, 0, spx1, wv, r0, c0, t1, a1, v1);
    if (has2) pref_A(x, Mb, b, 0, spx2, wv, r0, c0, t2, a2, v2);

    // ---- P2: msg_w -> LDS bf16, COALESCED float4 reads + scatter ds_writes ----
    {
        const float4* mw4 = (const float4*)msg_w;       // 4608 float4
#pragma unroll
        for (int k = 0; k < 18; ++k) {
            int idx4 = k * 256 + tid;
            float4 vv = mw4[idx4];
            int i0 = idx4 * 4;
            float ve[4] = {vv.x, vv.y, vv.z, vv.w};
#pragma unroll
            for (int e = 0; e < 4; ++e) {
                int i = i0 + e;
                int oc = i / 576, rem = i % 576;
                int icg = rem / 9, tap = rem % 9;
                int half = icg >> 5, ic = icg & 31;
                wmsg[((half * 9 + tap) * 32 + oc) * WPS + ic] = f2bf(ve[e]);
            }
        }
    }
    // ---- P3: mlp_w -> LDS bf16 (coalesced) ----
    {
        float4 vv = ((const float4*)mlp_w)[tid];        // 256 float4 = 1024 elems
        int i0 = tid * 4;
        float ve[4] = {vv.x, vv.y, vv.z, vv.w};
#pragma unroll
        for (int e = 0; e < 4; ++e) {
            int i = i0 + e;
            wmlp[(i >> 5) * WPS + (i & 31)] = f2bf(ve[e]);
        }
    }
    // ---- P4: masks for all j (inner 64 px, conv m-index order) ----
    for (int i = tid; i < LL * 64; i += 256) {
        int j = i >> 6, q = i & 63;
        int gr = r0 + 2 * (q >> 4) + ((q & 15) >> 3);
        int gc = c0 + (q & 7);
        int o00, o10, o01, o11;
        float a00, a10, a01, a11;
        bilin_weights(Mb + (size_t)j * 6, gr, gc, o00, o10, o01, o11, a00, a10, a01, a11);
        maskl[j][q] = a00 + a10 + a01 + a11;
    }
    // ---- P5: ego stage (consecutive lanes -> consecutive px within a cg) ----
    for (int u = tid; u < 400; u += 256) {
        int cg = u / 100, px = u % 100;
        stage_ego(x, b, px, cg, r0, c0, ego);
    }
    // ---- P6: combine + write j=0 ----
    pref_C(jbuf[0], spx1, wv, t1, a1, v1);
    if (has2) pref_C(jbuf[0], spx2, wv, t2, a2, v2);
    __syncthreads();

    f32x4 acce[2] = {};
    f32x4 agg[2];
#pragma unroll
    for (int r = 0; r < 4; ++r) { agg[0][r] = -INFINITY; agg[1][r] = -INFINITY; }

    for (int j = 0; j < LL; ++j) {
        // A) issue gather loads for j+1 (latency hides under conv)
        if (j < 4) {
            pref_A(x, Mb + (size_t)(j + 1) * 6, b, j + 1, spx1, wv, r0, c0, t1, a1, v1);
            if (has2) pref_A(x, Mb + (size_t)(j + 1) * 6, b, j + 1, spx2, wv, r0, c0, t2, a2, v2);
        }

        // B) conv j
        if (j == 0) {
            // ego half-conv (+ conv bias)
#pragma unroll
            for (int tap = 0; tap < 9; ++tap) {
                int dy = tap / 3 - 1, dx = tap % 3 - 1;
                int hp = (1 + 2 * wv + (lo >> 3) + dy) * HC + (1 + (lo & 7) + dx);
                bf16x8 Af = *(const bf16x8*)(ego + hp * IPS + kblk * 8);
#pragma unroll
                for (int nt = 0; nt < 2; ++nt) {
                    bf16x8 Bf = *(const bf16x8*)(wmsg + (size_t)((9 + tap) * 32 + nt * 16 + lo) * WPS + kblk * 8);
                    acce[nt] = __builtin_amdgcn_mfma_f32_16x16x32_bf16(Af, Bf, acce[nt], 0, 0, 0);
                }
            }
            float b0 = msg_b[lo], b1 = msg_b[16 + lo];
#pragma unroll
            for (int r = 0; r < 4; ++r) { acce[0][r] += b0; acce[1][r] += b1; }
        }
        {
            const unsigned short* jb = jbuf[j & 1];
            f32x4 acc[2] = {};
#pragma unroll
            for (int tap = 0; tap < 9; ++tap) {
                int dy = tap / 3 - 1, dx = tap % 3 - 1;
                int hp = (1 + 2 * wv + (lo >> 3) + dy) * HC + (1 + (lo & 7) + dx);
                bf16x8 Af = *(const bf16x8*)(jb + hp * IPS + kblk * 8);
#pragma unroll
                for (int nt = 0; nt < 2; ++nt) {
                    bf16x8 Bf = *(const bf16x8*)(wmsg + (size_t)(tap * 32 + nt * 16 + lo) * WPS + kblk * 8);
                    acc[nt] = __builtin_amdgcn_mfma_f32_16x16x32_bf16(Af, Bf, acc[nt], 0, 0, 0);
                }
            }
            f32x4 mk = *(const f32x4*)&maskl[j][wv * 16 + kblk * 4];
#pragma unroll
            for (int nt = 0; nt < 2; ++nt)
#pragma unroll
                for (int r = 0; r < 4; ++r)
                    agg[nt][r] = fmaxf(agg[nt][r], (acc[nt][r] + acce[nt][r]) * mk[r]);
        }

        // C) convert + LDS-write j+1
        if (j < 4) {
            pref_C(jbuf[(j + 1) & 1], spx1, wv, t1, a1, v1);
            if (has2) pref_C(jbuf[(j + 1) & 1], spx2, wv, t2, a2, v2);
        }
        __syncthreads();
    }

    // ---- epilogue: f = agg + x0(ego) -> per-wave LDS transpose (overlay jbuf) -> mlp MFMA ----
    float* fl = ((float*)jbuf) + wv * (16 * 40);   // 40-float row stride, 10240B <= 12800B
#pragma unroll
    for (int nt = 0; nt < 2; ++nt)
#pragma unroll
        for (int r = 0; r < 4; ++r) {
            int m = kblk * 4 + r;
            int hp = (1 + 2 * wv + (m >> 3)) * HC + 1 + (m & 7);
            float skip = bf2f(ego[hp * IPS + nt * 16 + lo]);
            fl[m * 40 + nt * 16 + lo] = agg[nt][r] + skip;
        }
    // same-wave read-back (lgkmcnt ordering; no cross-wave sharing)
    f32x4 q0 = *(const f32x4*)&fl[lo * 40 + kblk * 8];
    f32x4 q1 = *(const f32x4*)&fl[lo * 40 + kblk * 8 + 4];
    bf16x8 Afm;
#pragma unroll
    for (int e = 0; e < 4; ++e) {
        Afm[e]     = (short)f2bf(q0[e]);
        Afm[4 + e] = (short)f2bf(q1[e]);
    }
#pragma unroll
    for (int nt2 = 0; nt2 < 2; ++nt2) {
        bf16x8 Bm = *(const bf16x8*)(wmlp + (size_t)(nt2 * 16 + lo) * WPS + kblk * 8);
        f32x4 om = {};
        om = __builtin_amdgcn_mfma_f32_16x16x32_bf16(Afm, Bm, om, 0, 0, 0);
        float mb2 = mlp_b[nt2 * 16 + lo];
        int d = nt2 * 16 + lo;
#pragma unroll
        for (int r = 0; r < 4; ++r) {
            int m = kblk * 4 + r;
            int gr = r0 + 2 * wv + (m >> 3);
            int gc = c0 + (m & 7);
            out[((size_t)(b * CC + d)) * HWs + gr * WW + gc] = om[r] + mb2;
        }
    }
}

extern "C" void kernel_launch(void* const* d_in, const int* in_sizes, int n_in,
                              void* d_out, int out_size, void* d_ws, size_t ws_size,
                              hipStream_t stream)
{
    (void)in_sizes; (void)n_in; (void)out_size; (void)d_ws; (void)ws_size;
    const float* x     = (const float*)d_in[0];
    // d_in[1] = record_len (unused by reference)
    const float* M     = (const float*)d_in[2];
    const float* msg_w = (const float*)d_in[3];
    const float* msg_b = (const float*)d_in[4];
    const float* mlp_w = (const float*)d_in[5];
    const float* mlp_b = (const float*)d_in[6];
    float* out = (float*)d_out;

    dim3 g(WW / TC, HH / TR, BB);   // (22, 6, 2) = 264 blocks
    k_all<<<g, 256, 0, stream>>>(x, M, msg_w, msg_b, mlp_w, mlp_b, out);
}